// Round 17
// baseline (199.579 us; speedup 1.0000x reference)
//
#include <hip/hip_runtime.h>
#include <hip/hip_fp16.h>

#define N_NODES 100000
#define N_EDGESC 1600000
#define ETOT (N_EDGESC + N_NODES)
#define IN_CH 128
#define HID 64
#define OUTC 40
#define NEG_SLOPE 0.2f
#define BNODES 512                                   // nodes per bucket
#define NBUCK ((N_NODES + BNODES - 1) / BNODES)      // 196
#define BCAP 10240                                   // edge slots per bucket
#define TILE 8192                                    // edges per bucket1 block
#define EPT (TILE / 256)
#define NB1 ((ETOT + TILE - 1) / TILE)               // 208 bucket1 blocks
#define NG1 ((N_NODES + 127) / 128)                  // 782 gemm1 blocks

// ================= fused: bucket1 (sort pass 1) ∥ gemm1 — independent work =========
union FusedSmem {
    struct { int hist[256]; int lofs[256]; int gbase[256]; int cur[256]; int stage[TILE]; } b;
    struct { float Ws[IN_CH * HID]; float as_s[HID]; float ad_s[HID]; } g;
};

__global__ __launch_bounds__(256) void fused1_kernel(
    const int* __restrict__ src, const int* __restrict__ dst,
    int* __restrict__ bcur, int* __restrict__ buck,
    const float* __restrict__ x, const float* __restrict__ W1,
    const float* __restrict__ a_src, const float* __restrict__ a_dst,
    __half* __restrict__ h1, float* __restrict__ als, float* __restrict__ ald) {
    __shared__ FusedSmem sm;
    const int t = threadIdx.x;

    if (blockIdx.x < NB1) {
        // ---------------- bucket1 body ----------------
        const int t0 = blockIdx.x * TILE;
        sm.b.hist[t] = 0;
        __syncthreads();

        int payload[EPT];
        int bkt[EPT];
#pragma unroll
        for (int j = 0; j < EPT; j++) {
            int i = t0 + j * 256 + t;
            if (i < ETOT) {
                int s, d;
                if (i < N_EDGESC) { s = src[i]; d = dst[i]; } else { s = d = i - N_EDGESC; }
                int b = d / BNODES;
                bkt[j] = b;
                payload[j] = ((d & (BNODES - 1)) << 17) | s;
                atomicAdd(&sm.b.hist[b], 1);
            } else {
                bkt[j] = -1;
                payload[j] = 0;
            }
        }
        __syncthreads();

        int hv = sm.b.hist[t];
        sm.b.lofs[t] = hv;
        __syncthreads();
        for (int o = 1; o < 256; o <<= 1) {
            int v = (t >= o) ? sm.b.lofs[t - o] : 0;
            __syncthreads();
            sm.b.lofs[t] += v;
            __syncthreads();
        }
        sm.b.cur[t] = sm.b.lofs[t] - hv;
        if (t < NBUCK && hv > 0) sm.b.gbase[t] = t * BCAP + atomicAdd(&bcur[t * 16], hv);
        __syncthreads();

#pragma unroll
        for (int j = 0; j < EPT; j++) {
            if (bkt[j] >= 0) {
                int p = atomicAdd(&sm.b.cur[bkt[j]], 1);
                sm.b.stage[p] = payload[j];
            }
        }
        __syncthreads();

        const int wv = t >> 6;
        const int lane = t & 63;
        for (int b = wv; b < NBUCK; b += 4) {
            int cntb = sm.b.hist[b];
            if (cntb == 0) continue;
            int lo = sm.b.lofs[b] - cntb;
            int gb = sm.b.gbase[b];
            for (int k = lane; k < cntb; k += 64) buck[gb + k] = sm.b.stage[lo + k];
        }
    } else {
        // ---------------- gemm1 body (quad/2-nodes, 16 interleaved ch) ----------------
        for (int v = t; v < IN_CH * HID; v += 256) sm.g.Ws[v] = W1[v];
        if (t < HID) { sm.g.as_s[t] = a_src[t]; sm.g.ad_s[t] = a_dst[t]; }
        __syncthreads();
        const int n0 = (blockIdx.x - NB1) * 128 + (t >> 2) * 2;
        const int c = t & 3;
        if (n0 >= N_NODES) return;

        float acc0[16], acc1[16];
#pragma unroll
        for (int i = 0; i < 16; i++) { acc0[i] = 0.f; acc1[i] = 0.f; }

        const float4* xr0 = reinterpret_cast<const float4*>(x + (size_t)n0 * IN_CH);
        const float4* xr1 = reinterpret_cast<const float4*>(x + (size_t)(n0 + 1) * IN_CH);
#pragma unroll 2
        for (int kq = 0; kq < IN_CH / 4; kq++) {
            float4 xv0 = xr0[kq];
            float4 xv1 = xr1[kq];
#pragma unroll
            for (int jj = 0; jj < 4; jj++) {
                float xs0 = (jj == 0) ? xv0.x : (jj == 1) ? xv0.y : (jj == 2) ? xv0.z : xv0.w;
                float xs1 = (jj == 0) ? xv1.x : (jj == 1) ? xv1.y : (jj == 2) ? xv1.z : xv1.w;
                const float4* wr = reinterpret_cast<const float4*>(&sm.g.Ws[(kq * 4 + jj) * HID + c * 4]);
#pragma unroll
                for (int j = 0; j < 4; j++) {
                    float4 wv = wr[j * 4];
                    acc0[j * 4 + 0] += xs0 * wv.x; acc1[j * 4 + 0] += xs1 * wv.x;
                    acc0[j * 4 + 1] += xs0 * wv.y; acc1[j * 4 + 1] += xs1 * wv.y;
                    acc0[j * 4 + 2] += xs0 * wv.z; acc1[j * 4 + 2] += xs1 * wv.z;
                    acc0[j * 4 + 3] += xs0 * wv.w; acc1[j * 4 + 3] += xs1 * wv.w;
                }
            }
        }

        float s10 = 0.f, s20 = 0.f, s11 = 0.f, s21 = 0.f;
#pragma unroll
        for (int j = 0; j < 4; j++) {
            int cb = j * 16 + c * 4;
#pragma unroll
            for (int i = 0; i < 4; i++) {
                s10 += acc0[j * 4 + i] * sm.g.as_s[cb + i];
                s20 += acc0[j * 4 + i] * sm.g.ad_s[cb + i];
                s11 += acc1[j * 4 + i] * sm.g.as_s[cb + i];
                s21 += acc1[j * 4 + i] * sm.g.ad_s[cb + i];
            }
            union { __half2 h2[2]; uint2 u; } p0, p1;
            p0.h2[0] = __floats2half2_rn(acc0[j * 4 + 0], acc0[j * 4 + 1]);
            p0.h2[1] = __floats2half2_rn(acc0[j * 4 + 2], acc0[j * 4 + 3]);
            p1.h2[0] = __floats2half2_rn(acc1[j * 4 + 0], acc1[j * 4 + 1]);
            p1.h2[1] = __floats2half2_rn(acc1[j * 4 + 2], acc1[j * 4 + 3]);
            *reinterpret_cast<uint2*>(h1 + (size_t)n0 * HID + cb) = p0.u;
            *reinterpret_cast<uint2*>(h1 + (size_t)(n0 + 1) * HID + cb) = p1.u;
        }
        s10 += __shfl_xor(s10, 1); s10 += __shfl_xor(s10, 2);
        s20 += __shfl_xor(s20, 1); s20 += __shfl_xor(s20, 2);
        s11 += __shfl_xor(s11, 1); s11 += __shfl_xor(s11, 2);
        s21 += __shfl_xor(s21, 1); s21 += __shfl_xor(s21, 2);
        if (c == 0) {
            als[n0] = s10; ald[n0] = s20;
            als[n0 + 1] = s11; ald[n0 + 1] = s21;
        }
    }
}

// ---- pass 2 (512 threads): one block per bucket; local histogram+scan; LDS-cursor scatter ----
__global__ __launch_bounds__(512) void bucket2_kernel(const int* __restrict__ bcur,
                                                      const int* __restrict__ buck,
                                                      int* __restrict__ ssrc,
                                                      int* __restrict__ off,
                                                      int* __restrict__ deg) {
    __shared__ int h5[BNODES];
    __shared__ int sdata[256];
    __shared__ int lcur[BNODES];
    const int b = blockIdx.x;
    const int t = threadIdx.x;
    const int base0 = b * BNODES;
    const int bbase = b * BCAP;
    const int cnt_b = bcur[b * 16];           // count (bases were b*BCAP + count)

    h5[t] = 0;
    __syncthreads();
    for (int i = t; i < cnt_b; i += 512) atomicAdd(&h5[buck[bbase + i] >> 17], 1);
    __syncthreads();

    int c0 = 0, c1 = 0, s = 0;
    if (t < 256) {
        c0 = h5[2 * t]; c1 = h5[2 * t + 1];
        s = c0 + c1;
        sdata[t] = s;
    }
    __syncthreads();
    for (int o = 1; o < 256; o <<= 1) {
        int v = (t < 256 && t >= o) ? sdata[t - o] : 0;
        __syncthreads();
        if (t < 256) sdata[t] += v;
        __syncthreads();
    }
    if (t < 256) {
        int run = sdata[t] - s;
        int e0 = bbase + run, e1 = bbase + run + c0;
        int n0 = base0 + 2 * t, n1 = n0 + 1;
        if (n0 < N_NODES) { off[n0] = e0; deg[n0] = c0; }
        if (n1 < N_NODES) { off[n1] = e1; deg[n1] = c1; }
        lcur[2 * t] = e0; lcur[2 * t + 1] = e1;
    }
    __syncthreads();

    for (int i = t; i < cnt_b; i += 512) {
        int w = buck[bbase + i];
        int pos = atomicAdd(&lcur[w >> 17], 1);
        ssrc[pos] = w & 0x1FFFF;
    }
}

// ================= agg v7: prefetched gather + fused gemm2 epilogue (MODE 0) =========
// MODE 0 (C=64): layer-1 agg; epilogue computes h2 = relu(agg+b1) @ W2 (64x40),
//   logits als2/ald2, writes h2 (fp16) — replaces the separate gemm2 kernel.
// MODE 1 (C=40): layer-2 agg + log_softmax (final output).
__device__ __forceinline__ __half2 shfl_xor_h2(__half2 v, int o) {
    int i = *reinterpret_cast<int*>(&v);
    i = __shfl_xor(i, o);
    return *reinterpret_cast<__half2*>(&i);
}

template <int C, int MODE, typename OutT>
__global__ __launch_bounds__(256) void agg_kernel(
    const int* __restrict__ off, const int* __restrict__ degs,
    const int* __restrict__ ssrc,
    const float* __restrict__ als, const float* __restrict__ ald,
    const __half* __restrict__ h, const float* __restrict__ bias,
    const float* __restrict__ W2, const float* __restrict__ as2, const float* __restrict__ ad2,
    OutT* __restrict__ outp, float* __restrict__ als_o, float* __restrict__ ald_o) {
    __shared__ float Ws2[(MODE == 0) ? (64 * 41) : 1];   // pad stride 41 vs row 40
    __shared__ float a2s[(MODE == 0) ? 40 : 1];
    __shared__ float a2d[(MODE == 0) ? 40 : 1];
    if (MODE == 0) {
        for (int v = threadIdx.x; v < HID * OUTC; v += 256) {
            int k = v / OUTC, j = v - k * OUTC;
            Ws2[k * 41 + j] = W2[v];
        }
        if (threadIdx.x < OUTC) { a2s[threadIdx.x] = as2[threadIdx.x]; a2d[threadIdx.x] = ad2[threadIdx.x]; }
        __syncthreads();
    }

    const int lane = threadIdx.x & 63;
    const int d = (blockIdx.x * 256 + threadIdx.x) >> 6;
    if (d >= N_NODES) return;
    const int o0 = off[d];
    const int deg = degs[d];
    const float aldd = ald[d];

    // ---- lane t owns edge t: src + unnormalized weight ----
    int myS = 0;
    float myW = 0.f;
    if (lane < deg) {
        myS = ssrc[o0 + lane];
        float e = als[myS] + aldd;
        e = e > 0.f ? e : NEG_SLOPE * e;
        myW = __expf(e);
    }

    constexpr int GL = (C + 7) / 8;
    const int g = lane >> 3;
    const int gl = lane & 7;
    const bool lactive = (gl < GL);
    const int dmax = min(deg, 64);

    // ---- prefetch first 32 edges' h rows BEFORE the reduce ----
    int ps0 = __shfl(myS, g);
    int ps1 = __shfl(myS, 8 + g);
    int ps2 = __shfl(myS, 16 + g);
    int ps3 = __shfl(myS, 24 + g);
    const bool pv0 = lactive && (g < dmax);
    const bool pv1 = lactive && (8 + g < dmax);
    const bool pv2 = lactive && (16 + g < dmax);
    const bool pv3 = lactive && (24 + g < dmax);
    uint4 P0 = {0, 0, 0, 0}, P1 = P0, P2 = P0, P3 = P0;
    if (pv0) P0 = *reinterpret_cast<const uint4*>(h + (size_t)ps0 * C + 8 * gl);
    if (pv1) P1 = *reinterpret_cast<const uint4*>(h + (size_t)ps1 * C + 8 * gl);
    if (pv2) P2 = *reinterpret_cast<const uint4*>(h + (size_t)ps2 * C + 8 * gl);
    if (pv3) P3 = *reinterpret_cast<const uint4*>(h + (size_t)ps3 * C + 8 * gl);

    // ---- softmax denominator (overlaps with the in-flight prefetches) ----
    float sloc = myW;
    for (int t = 64 + lane; t < deg; t += 64) {
        int s = ssrc[o0 + t];
        float e = als[s] + aldd;
        e = e > 0.f ? e : NEG_SLOPE * e;
        sloc += __expf(e);
    }
#pragma unroll
    for (int o = 32; o; o >>= 1) sloc += __shfl_xor(sloc, o);
    const float inv = 1.0f / (sloc + 1e-16f);
    __half2 mywn2 = __float2half2_rn(myW * inv);
    const int myWbits = *reinterpret_cast<const int*>(&mywn2);

    __half2 a0 = __float2half2_rn(0.f), a1 = a0, a2 = a0, a3 = a0;
    auto fmaP = [&](uint4 u, int wbits) {
        __half2 wn2 = *reinterpret_cast<__half2*>(&wbits);
        union { uint4 u4; __half2 h2[4]; } uu;
        uu.u4 = u;
        a0 = __hfma2(uu.h2[0], wn2, a0);
        a1 = __hfma2(uu.h2[1], wn2, a1);
        a2 = __hfma2(uu.h2[2], wn2, a2);
        a3 = __hfma2(uu.h2[3], wn2, a3);
    };
    auto body = [&](int s, int wbits) {
        uint4 u = *reinterpret_cast<const uint4*>(h + (size_t)s * C + 8 * gl);
        fmaP(u, wbits);
    };

    {
        int w0 = __shfl(myWbits, g);
        int w1 = __shfl(myWbits, 8 + g);
        int w2 = __shfl(myWbits, 16 + g);
        int w3 = __shfl(myWbits, 24 + g);
        if (pv0) fmaP(P0, w0);
        if (pv1) fmaP(P1, w1);
        if (pv2) fmaP(P2, w2);
        if (pv3) fmaP(P3, w3);
    }
    for (int base = 32; base < dmax; base += 16) {
        int t0 = base + g;
        int t1 = base + 8 + g;
        int s0 = __shfl(myS, t0 & 63), w0 = __shfl(myWbits, t0 & 63);
        int s1 = __shfl(myS, t1 & 63), w1 = __shfl(myWbits, t1 & 63);
        if (lactive && t0 < dmax) body(s0, w0);
        if (lactive && t1 < dmax) body(s1, w1);
    }
    for (int t2 = 64 + g; t2 < deg; t2 += 8) {
        int s = ssrc[o0 + t2];
        float e = als[s] + aldd;
        e = e > 0.f ? e : NEG_SLOPE * e;
        __half2 wn2 = __float2half2_rn(__expf(e) * inv);
        if (lactive) body(s, *reinterpret_cast<int*>(&wn2));
    }

#pragma unroll
    for (int o = 8; o <= 32; o <<= 1) {
        a0 = __hadd2(a0, shfl_xor_h2(a0, o));
        a1 = __hadd2(a1, shfl_xor_h2(a1, o));
        a2 = __hadd2(a2, shfl_xor_h2(a2, o));
        a3 = __hadd2(a3, shfl_xor_h2(a3, o));
    }

    float2 f0 = __half22float2(a0), f1 = __half22float2(a1);
    float2 f2 = __half22float2(a2), f3 = __half22float2(a3);

    if (MODE == 0) {
        // ---- fused gemm2 epilogue ----
        // every lane holds channels 8*gl..8*gl+7 (replicated across g)
        const float4 b0 = reinterpret_cast<const float4*>(bias)[2 * gl];
        const float4 b1v = reinterpret_cast<const float4*>(bias)[2 * gl + 1];
        float v[8];
        v[0] = fmaxf(f0.x + b0.x, 0.f); v[1] = fmaxf(f0.y + b0.y, 0.f);
        v[2] = fmaxf(f1.x + b0.z, 0.f); v[3] = fmaxf(f1.y + b0.w, 0.f);
        v[4] = fmaxf(f2.x + b1v.x, 0.f); v[5] = fmaxf(f2.y + b1v.y, 0.f);
        v[6] = fmaxf(f3.x + b1v.z, 0.f); v[7] = fmaxf(f3.y + b1v.w, 0.f);
        // lane (g,gl): partial out[5g+jj] from its own octet k=8*gl+i
        float part[5];
#pragma unroll
        for (int jj = 0; jj < 5; jj++) part[jj] = 0.f;
#pragma unroll
        for (int i = 0; i < 8; i++) {
            const float* wrow = &Ws2[(8 * gl + i) * 41 + 5 * g];
#pragma unroll
            for (int jj = 0; jj < 5; jj++) part[jj] += v[i] * wrow[jj];
        }
        // reduce across gl (lane bits 0..2)
#pragma unroll
        for (int o = 1; o <= 4; o <<= 1) {
#pragma unroll
            for (int jj = 0; jj < 5; jj++) part[jj] += __shfl_xor(part[jj], o);
        }
        // gl==0 lanes hold out[5g..5g+5)
        float p1 = 0.f, p2 = 0.f;
        if (gl == 0) {
#pragma unroll
            for (int jj = 0; jj < 5; jj++) {
                p1 += part[jj] * a2s[5 * g + jj];
                p2 += part[jj] * a2d[5 * g + jj];
            }
        }
#pragma unroll
        for (int o = 8; o <= 32; o <<= 1) { p1 += __shfl_xor(p1, o); p2 += __shfl_xor(p2, o); }
        if (lane == 0) { als_o[d] = p1; ald_o[d] = p2; }
        if (gl == 0) {
            __half* orow = reinterpret_cast<__half*>(outp) + (size_t)d * OUTC + 5 * g;
#pragma unroll
            for (int jj = 0; jj < 5; jj++) orow[jj] = __float2half(part[jj]);
        }
    } else {
        const bool valid = (g == 0) && lactive;
        float v[8];
        float mm = -1e30f;
        if (valid) {
            const float4 b0 = reinterpret_cast<const float4*>(bias)[2 * gl];
            const float4 b1v = reinterpret_cast<const float4*>(bias)[2 * gl + 1];
            v[0] = f0.x + b0.x; v[1] = f0.y + b0.y; v[2] = f1.x + b0.z; v[3] = f1.y + b0.w;
            v[4] = f2.x + b1v.x; v[5] = f2.y + b1v.y; v[6] = f3.x + b1v.z; v[7] = f3.y + b1v.w;
#pragma unroll
            for (int j = 0; j < 8; j++) mm = fmaxf(mm, v[j]);
        }
#pragma unroll
        for (int o = 1; o <= 4; o <<= 1) mm = fmaxf(mm, __shfl_xor(mm, o));
        float ex = 0.f;
        if (valid) {
#pragma unroll
            for (int j = 0; j < 8; j++) ex += __expf(v[j] - mm);
        }
#pragma unroll
        for (int o = 1; o <= 4; o <<= 1) ex += __shfl_xor(ex, o);
        if (valid) {
            float lse = mm + logf(ex);
            float4 o0v, o1v;
            o0v.x = v[0] - lse; o0v.y = v[1] - lse; o0v.z = v[2] - lse; o0v.w = v[3] - lse;
            o1v.x = v[4] - lse; o1v.y = v[5] - lse; o1v.z = v[6] - lse; o1v.w = v[7] - lse;
            float* orow = reinterpret_cast<float*>(outp) + (size_t)d * C + 8 * gl;
            *reinterpret_cast<float4*>(orow) = o0v;
            *reinterpret_cast<float4*>(orow + 4) = o1v;
        }
    }
}

extern "C" void kernel_launch(void* const* d_in, const int* in_sizes, int n_in,
                              void* d_out, int out_size, void* d_ws, size_t ws_size,
                              hipStream_t stream) {
    const float* x   = (const float*)d_in[0];
    const int*   ei  = (const int*)d_in[1];
    const float* W1  = (const float*)d_in[2];
    const float* as1 = (const float*)d_in[3];
    const float* ad1 = (const float*)d_in[4];
    const float* b1  = (const float*)d_in[5];
    const float* W2  = (const float*)d_in[6];
    const float* as2 = (const float*)d_in[7];
    const float* ad2 = (const float*)d_in[8];
    const float* b2  = (const float*)d_in[9];
    float* out = (float*)d_out;

    char* p = (char*)d_ws;
    auto alloc = [&](size_t bytes) { void* r = p; p += (bytes + 63) & ~(size_t)63; return r; };

    __half* h16 = (__half*)alloc((size_t)N_NODES * 64 * sizeof(__half));   // layer-1 h
    int* buck   = (int*)alloc((size_t)NBUCK * BCAP * sizeof(int));
    __half* B16 = (__half*)alloc((size_t)N_NODES * 64 * sizeof(__half));   // h2 (40ch rows)
    float* als  = (float*)alloc((size_t)N_NODES * sizeof(float));
    float* ald  = (float*)alloc((size_t)N_NODES * sizeof(float));
    float* als_b = (float*)alloc((size_t)N_NODES * sizeof(float));
    float* ald_b = (float*)alloc((size_t)N_NODES * sizeof(float));
    int* off    = (int*)alloc((size_t)N_NODES * sizeof(int));
    int* deg    = (int*)alloc((size_t)N_NODES * sizeof(int));
    int* bcur   = (int*)alloc((size_t)NBUCK * 16 * sizeof(int));
    int* ssrc   = (int*)alloc((size_t)NBUCK * BCAP * sizeof(int));

    const int* srcA = ei;
    const int* dstA = ei + N_EDGESC;

    hipMemsetAsync(bcur, 0, (size_t)NBUCK * 16 * sizeof(int), stream);
    fused1_kernel<<<NB1 + NG1, 256, 0, stream>>>(srcA, dstA, bcur, buck,
                                                 x, W1, as1, ad1, h16, als, ald);
    bucket2_kernel<<<NBUCK, 512, 0, stream>>>(bcur, buck, ssrc, off, deg);

    // ---- layer 1 agg + fused gemm2 (writes h2=B16, logits als_b/ald_b) ----
    agg_kernel<HID, 0, __half><<<(N_NODES + 3) / 4, 256, 0, stream>>>(
        off, deg, ssrc, als, ald, h16, b1, W2, as2, ad2, B16, als_b, ald_b);

    // ---- layer 2 agg + log_softmax ----
    agg_kernel<OUTC, 1, float><<<(N_NODES + 3) / 4, 256, 0, stream>>>(
        off, deg, ssrc, als_b, ald_b, B16, b2, nullptr, nullptr, nullptr, out, nullptr, nullptr);
}

// Round 18
// 165.472 us; speedup vs baseline: 1.2061x; 1.2061x over previous
//
#include <hip/hip_runtime.h>
#include <hip/hip_fp16.h>

#define N_NODES 100000
#define N_EDGESC 1600000
#define ETOT (N_EDGESC + N_NODES)
#define IN_CH 128
#define HID 64
#define OUTC 40
#define NEG_SLOPE 0.2f
#define BNODES 512                                   // nodes per bucket
#define NBUCK ((N_NODES + BNODES - 1) / BNODES)      // 196
#define BCAP 10240                                   // edge slots per bucket
#define TILE 8192                                    // edges per bucket1 block
#define EPT (TILE / 256)
#define NB1 ((ETOT + TILE - 1) / TILE)               // 208 bucket1 blocks
#define NG1 ((N_NODES + 127) / 128)                  // 782 gemm1 blocks

// ================= fused: bucket1 (sort pass 1) ∥ gemm1 — independent work =========
union FusedSmem {
    struct { int hist[256]; int lofs[256]; int gbase[256]; int cur[256]; int stage[TILE]; } b;
    struct { float Ws[IN_CH * HID]; float as_s[HID]; float ad_s[HID]; } g;
};

__global__ __launch_bounds__(256) void fused1_kernel(
    const int* __restrict__ src, const int* __restrict__ dst,
    int* __restrict__ bcur, int* __restrict__ buck,
    const float* __restrict__ x, const float* __restrict__ W1,
    const float* __restrict__ a_src, const float* __restrict__ a_dst,
    __half* __restrict__ h1, float* __restrict__ als, float* __restrict__ ald) {
    __shared__ FusedSmem sm;
    const int t = threadIdx.x;

    if (blockIdx.x < NB1) {
        // ---------------- bucket1 body ----------------
        const int t0 = blockIdx.x * TILE;
        sm.b.hist[t] = 0;
        __syncthreads();

        int payload[EPT];
        int bkt[EPT];
#pragma unroll
        for (int j = 0; j < EPT; j++) {
            int i = t0 + j * 256 + t;
            if (i < ETOT) {
                int s, d;
                if (i < N_EDGESC) { s = src[i]; d = dst[i]; } else { s = d = i - N_EDGESC; }
                int b = d / BNODES;
                bkt[j] = b;
                payload[j] = ((d & (BNODES - 1)) << 17) | s;
                atomicAdd(&sm.b.hist[b], 1);
            } else {
                bkt[j] = -1;
                payload[j] = 0;
            }
        }
        __syncthreads();

        int hv = sm.b.hist[t];
        sm.b.lofs[t] = hv;
        __syncthreads();
        for (int o = 1; o < 256; o <<= 1) {
            int v = (t >= o) ? sm.b.lofs[t - o] : 0;
            __syncthreads();
            sm.b.lofs[t] += v;
            __syncthreads();
        }
        sm.b.cur[t] = sm.b.lofs[t] - hv;
        if (t < NBUCK && hv > 0) sm.b.gbase[t] = t * BCAP + atomicAdd(&bcur[t * 16], hv);
        __syncthreads();

#pragma unroll
        for (int j = 0; j < EPT; j++) {
            if (bkt[j] >= 0) {
                int p = atomicAdd(&sm.b.cur[bkt[j]], 1);
                sm.b.stage[p] = payload[j];
            }
        }
        __syncthreads();

        const int wv = t >> 6;
        const int lane = t & 63;
        for (int b = wv; b < NBUCK; b += 4) {
            int cntb = sm.b.hist[b];
            if (cntb == 0) continue;
            int lo = sm.b.lofs[b] - cntb;
            int gb = sm.b.gbase[b];
            for (int k = lane; k < cntb; k += 64) buck[gb + k] = sm.b.stage[lo + k];
        }
    } else {
        // ---------------- gemm1 body (quad/2-nodes, 16 interleaved ch) ----------------
        for (int v = t; v < IN_CH * HID; v += 256) sm.g.Ws[v] = W1[v];
        if (t < HID) { sm.g.as_s[t] = a_src[t]; sm.g.ad_s[t] = a_dst[t]; }
        __syncthreads();
        const int n0 = (blockIdx.x - NB1) * 128 + (t >> 2) * 2;
        const int c = t & 3;
        if (n0 >= N_NODES) return;

        float acc0[16], acc1[16];
#pragma unroll
        for (int i = 0; i < 16; i++) { acc0[i] = 0.f; acc1[i] = 0.f; }

        const float4* xr0 = reinterpret_cast<const float4*>(x + (size_t)n0 * IN_CH);
        const float4* xr1 = reinterpret_cast<const float4*>(x + (size_t)(n0 + 1) * IN_CH);
#pragma unroll 2
        for (int kq = 0; kq < IN_CH / 4; kq++) {
            float4 xv0 = xr0[kq];
            float4 xv1 = xr1[kq];
#pragma unroll
            for (int jj = 0; jj < 4; jj++) {
                float xs0 = (jj == 0) ? xv0.x : (jj == 1) ? xv0.y : (jj == 2) ? xv0.z : xv0.w;
                float xs1 = (jj == 0) ? xv1.x : (jj == 1) ? xv1.y : (jj == 2) ? xv1.z : xv1.w;
                const float4* wr = reinterpret_cast<const float4*>(&sm.g.Ws[(kq * 4 + jj) * HID + c * 4]);
#pragma unroll
                for (int j = 0; j < 4; j++) {
                    float4 wv = wr[j * 4];
                    acc0[j * 4 + 0] += xs0 * wv.x; acc1[j * 4 + 0] += xs1 * wv.x;
                    acc0[j * 4 + 1] += xs0 * wv.y; acc1[j * 4 + 1] += xs1 * wv.y;
                    acc0[j * 4 + 2] += xs0 * wv.z; acc1[j * 4 + 2] += xs1 * wv.z;
                    acc0[j * 4 + 3] += xs0 * wv.w; acc1[j * 4 + 3] += xs1 * wv.w;
                }
            }
        }

        float s10 = 0.f, s20 = 0.f, s11 = 0.f, s21 = 0.f;
#pragma unroll
        for (int j = 0; j < 4; j++) {
            int cb = j * 16 + c * 4;
#pragma unroll
            for (int i = 0; i < 4; i++) {
                s10 += acc0[j * 4 + i] * sm.g.as_s[cb + i];
                s20 += acc0[j * 4 + i] * sm.g.ad_s[cb + i];
                s11 += acc1[j * 4 + i] * sm.g.as_s[cb + i];
                s21 += acc1[j * 4 + i] * sm.g.ad_s[cb + i];
            }
            union { __half2 h2[2]; uint2 u; } p0, p1;
            p0.h2[0] = __floats2half2_rn(acc0[j * 4 + 0], acc0[j * 4 + 1]);
            p0.h2[1] = __floats2half2_rn(acc0[j * 4 + 2], acc0[j * 4 + 3]);
            p1.h2[0] = __floats2half2_rn(acc1[j * 4 + 0], acc1[j * 4 + 1]);
            p1.h2[1] = __floats2half2_rn(acc1[j * 4 + 2], acc1[j * 4 + 3]);
            *reinterpret_cast<uint2*>(h1 + (size_t)n0 * HID + cb) = p0.u;
            *reinterpret_cast<uint2*>(h1 + (size_t)(n0 + 1) * HID + cb) = p1.u;
        }
        s10 += __shfl_xor(s10, 1); s10 += __shfl_xor(s10, 2);
        s20 += __shfl_xor(s20, 1); s20 += __shfl_xor(s20, 2);
        s11 += __shfl_xor(s11, 1); s11 += __shfl_xor(s11, 2);
        s21 += __shfl_xor(s21, 1); s21 += __shfl_xor(s21, 2);
        if (c == 0) {
            als[n0] = s10; ald[n0] = s20;
            als[n0 + 1] = s11; ald[n0 + 1] = s21;
        }
    }
}

// ---- pass 2 (512 threads): one block per bucket; local histogram+scan; LDS-cursor scatter ----
__global__ __launch_bounds__(512) void bucket2_kernel(const int* __restrict__ bcur,
                                                      const int* __restrict__ buck,
                                                      int* __restrict__ ssrc,
                                                      int* __restrict__ off,
                                                      int* __restrict__ deg) {
    __shared__ int h5[BNODES];
    __shared__ int sdata[256];
    __shared__ int lcur[BNODES];
    const int b = blockIdx.x;
    const int t = threadIdx.x;
    const int base0 = b * BNODES;
    const int bbase = b * BCAP;
    const int cnt_b = bcur[b * 16];           // count (bases were b*BCAP + count)

    h5[t] = 0;
    __syncthreads();
    for (int i = t; i < cnt_b; i += 512) atomicAdd(&h5[buck[bbase + i] >> 17], 1);
    __syncthreads();

    int c0 = 0, c1 = 0, s = 0;
    if (t < 256) {
        c0 = h5[2 * t]; c1 = h5[2 * t + 1];
        s = c0 + c1;
        sdata[t] = s;
    }
    __syncthreads();
    for (int o = 1; o < 256; o <<= 1) {
        int v = (t < 256 && t >= o) ? sdata[t - o] : 0;
        __syncthreads();
        if (t < 256) sdata[t] += v;
        __syncthreads();
    }
    if (t < 256) {
        int run = sdata[t] - s;
        int e0 = bbase + run, e1 = bbase + run + c0;
        int n0 = base0 + 2 * t, n1 = n0 + 1;
        if (n0 < N_NODES) { off[n0] = e0; deg[n0] = c0; }
        if (n1 < N_NODES) { off[n1] = e1; deg[n1] = c1; }
        lcur[2 * t] = e0; lcur[2 * t + 1] = e1;
    }
    __syncthreads();

    for (int i = t; i < cnt_b; i += 512) {
        int w = buck[bbase + i];
        int pos = atomicAdd(&lcur[w >> 17], 1);
        ssrc[pos] = w & 0x1FFFF;
    }
}

// ================= GEMM2: quad/2-nodes, 10 interleaved ch, W-read reuse x2 =========
__global__ __launch_bounds__(256) void gemm2_kernel(
    const __half* __restrict__ hin, const float* __restrict__ W2,
    const float* __restrict__ a_src, const float* __restrict__ a_dst,
    __half* __restrict__ h2, float* __restrict__ als, float* __restrict__ ald) {
    __shared__ float Ws[HID * OUTC];
    __shared__ float as_s[OUTC], ad_s[OUTC];
    for (int v = threadIdx.x; v < HID * OUTC; v += 256) Ws[v] = W2[v];
    if (threadIdx.x < OUTC) { as_s[threadIdx.x] = a_src[threadIdx.x]; ad_s[threadIdx.x] = a_dst[threadIdx.x]; }
    __syncthreads();
    const int t = threadIdx.x;
    const int n0 = blockIdx.x * 128 + (t >> 2) * 2;
    const int c = t & 3;
    if (n0 >= N_NODES) return;

    float acc0[10], acc1[10];
#pragma unroll
    for (int i = 0; i < 10; i++) { acc0[i] = 0.f; acc1[i] = 0.f; }

    const uint4* xr0 = reinterpret_cast<const uint4*>(hin + (size_t)n0 * HID);
    const uint4* xr1 = reinterpret_cast<const uint4*>(hin + (size_t)(n0 + 1) * HID);
#pragma unroll
    for (int kq = 0; kq < HID / 8; kq++) {
        union { uint4 u; __half2 h[4]; } u0, u1;
        u0.u = xr0[kq];
        u1.u = xr1[kq];
        float x0[8], x1[8];
#pragma unroll
        for (int j = 0; j < 4; j++) {
            float2 f0 = __half22float2(u0.h[j]);
            float2 f1 = __half22float2(u1.h[j]);
            x0[2 * j] = f0.x; x0[2 * j + 1] = f0.y;
            x1[2 * j] = f1.x; x1[2 * j + 1] = f1.y;
        }
#pragma unroll
        for (int jj = 0; jj < 8; jj++) {
            float xs0 = x0[jj], xs1 = x1[jj];
            const float2* wr = reinterpret_cast<const float2*>(&Ws[(kq * 8 + jj) * OUTC + c * 2]);
#pragma unroll
            for (int j = 0; j < 5; j++) {
                float2 wv = wr[j * 4];
                acc0[j * 2 + 0] += xs0 * wv.x; acc1[j * 2 + 0] += xs1 * wv.x;
                acc0[j * 2 + 1] += xs0 * wv.y; acc1[j * 2 + 1] += xs1 * wv.y;
            }
        }
    }

    float s10 = 0.f, s20 = 0.f, s11 = 0.f, s21 = 0.f;
#pragma unroll
    for (int j = 0; j < 5; j++) {
        int cb = j * 8 + c * 2;
        s10 += acc0[j * 2 + 0] * as_s[cb] + acc0[j * 2 + 1] * as_s[cb + 1];
        s20 += acc0[j * 2 + 0] * ad_s[cb] + acc0[j * 2 + 1] * ad_s[cb + 1];
        s11 += acc1[j * 2 + 0] * as_s[cb] + acc1[j * 2 + 1] * as_s[cb + 1];
        s21 += acc1[j * 2 + 0] * ad_s[cb] + acc1[j * 2 + 1] * ad_s[cb + 1];
        __half2 p0 = __floats2half2_rn(acc0[j * 2 + 0], acc0[j * 2 + 1]);
        __half2 p1 = __floats2half2_rn(acc1[j * 2 + 0], acc1[j * 2 + 1]);
        *reinterpret_cast<unsigned*>(h2 + (size_t)n0 * OUTC + cb) = *reinterpret_cast<unsigned*>(&p0);
        *reinterpret_cast<unsigned*>(h2 + (size_t)(n0 + 1) * OUTC + cb) = *reinterpret_cast<unsigned*>(&p1);
    }
    s10 += __shfl_xor(s10, 1); s10 += __shfl_xor(s10, 2);
    s20 += __shfl_xor(s20, 1); s20 += __shfl_xor(s20, 2);
    s11 += __shfl_xor(s11, 1); s11 += __shfl_xor(s11, 2);
    s21 += __shfl_xor(s21, 1); s21 += __shfl_xor(s21, 2);
    if (c == 0) {
        als[n0] = s10; ald[n0] = s20;
        als[n0 + 1] = s11; ald[n0 + 1] = s21;
    }
}

// ================= agg v6: first 32 edge-gathers prefetched BEFORE the softmax reduce ====
__device__ __forceinline__ __half2 shfl_xor_h2(__half2 v, int o) {
    int i = *reinterpret_cast<int*>(&v);
    i = __shfl_xor(i, o);
    return *reinterpret_cast<__half2*>(&i);
}

template <int C, bool FINAL, typename OutT>
__global__ __launch_bounds__(256) void agg_kernel(
    const int* __restrict__ off, const int* __restrict__ degs,
    const int* __restrict__ ssrc,
    const float* __restrict__ als, const float* __restrict__ ald,
    const __half* __restrict__ h, const float* __restrict__ bias,
    OutT* __restrict__ outp) {
    const int lane = threadIdx.x & 63;
    const int d = (blockIdx.x * 256 + threadIdx.x) >> 6;
    if (d >= N_NODES) return;
    const int o0 = off[d];
    const int deg = degs[d];
    const float aldd = ald[d];

    int myS = 0;
    float myW = 0.f;
    if (lane < deg) {
        myS = ssrc[o0 + lane];
        float e = als[myS] + aldd;
        e = e > 0.f ? e : NEG_SLOPE * e;
        myW = __expf(e);
    }

    constexpr int GL = (C + 7) / 8;
    const int g = lane >> 3;
    const int gl = lane & 7;
    const bool lactive = (gl < GL);
    const int dmax = min(deg, 64);

    int ps0 = __shfl(myS, g);
    int ps1 = __shfl(myS, 8 + g);
    int ps2 = __shfl(myS, 16 + g);
    int ps3 = __shfl(myS, 24 + g);
    const bool pv0 = lactive && (g < dmax);
    const bool pv1 = lactive && (8 + g < dmax);
    const bool pv2 = lactive && (16 + g < dmax);
    const bool pv3 = lactive && (24 + g < dmax);
    uint4 P0 = {0, 0, 0, 0}, P1 = P0, P2 = P0, P3 = P0;
    if (pv0) P0 = *reinterpret_cast<const uint4*>(h + (size_t)ps0 * C + 8 * gl);
    if (pv1) P1 = *reinterpret_cast<const uint4*>(h + (size_t)ps1 * C + 8 * gl);
    if (pv2) P2 = *reinterpret_cast<const uint4*>(h + (size_t)ps2 * C + 8 * gl);
    if (pv3) P3 = *reinterpret_cast<const uint4*>(h + (size_t)ps3 * C + 8 * gl);

    float sloc = myW;
    for (int t = 64 + lane; t < deg; t += 64) {
        int s = ssrc[o0 + t];
        float e = als[s] + aldd;
        e = e > 0.f ? e : NEG_SLOPE * e;
        sloc += __expf(e);
    }
#pragma unroll
    for (int o = 32; o; o >>= 1) sloc += __shfl_xor(sloc, o);
    const float inv = 1.0f / (sloc + 1e-16f);
    __half2 mywn2 = __float2half2_rn(myW * inv);
    const int myWbits = *reinterpret_cast<const int*>(&mywn2);

    __half2 a0 = __float2half2_rn(0.f), a1 = a0, a2 = a0, a3 = a0;
    auto fmaP = [&](uint4 u, int wbits) {
        __half2 wn2 = *reinterpret_cast<__half2*>(&wbits);
        union { uint4 u4; __half2 h2[4]; } uu;
        uu.u4 = u;
        a0 = __hfma2(uu.h2[0], wn2, a0);
        a1 = __hfma2(uu.h2[1], wn2, a1);
        a2 = __hfma2(uu.h2[2], wn2, a2);
        a3 = __hfma2(uu.h2[3], wn2, a3);
    };
    auto body = [&](int s, int wbits) {
        uint4 u = *reinterpret_cast<const uint4*>(h + (size_t)s * C + 8 * gl);
        fmaP(u, wbits);
    };

    {
        int w0 = __shfl(myWbits, g);
        int w1 = __shfl(myWbits, 8 + g);
        int w2 = __shfl(myWbits, 16 + g);
        int w3 = __shfl(myWbits, 24 + g);
        if (pv0) fmaP(P0, w0);
        if (pv1) fmaP(P1, w1);
        if (pv2) fmaP(P2, w2);
        if (pv3) fmaP(P3, w3);
    }
    for (int base = 32; base < dmax; base += 16) {
        int t0 = base + g;
        int t1 = base + 8 + g;
        int s0 = __shfl(myS, t0 & 63), w0 = __shfl(myWbits, t0 & 63);
        int s1 = __shfl(myS, t1 & 63), w1 = __shfl(myWbits, t1 & 63);
        if (lactive && t0 < dmax) body(s0, w0);
        if (lactive && t1 < dmax) body(s1, w1);
    }
    for (int t2 = 64 + g; t2 < deg; t2 += 8) {
        int s = ssrc[o0 + t2];
        float e = als[s] + aldd;
        e = e > 0.f ? e : NEG_SLOPE * e;
        __half2 wn2 = __float2half2_rn(__expf(e) * inv);
        if (lactive) body(s, *reinterpret_cast<int*>(&wn2));
    }

#pragma unroll
    for (int o = 8; o <= 32; o <<= 1) {
        a0 = __hadd2(a0, shfl_xor_h2(a0, o));
        a1 = __hadd2(a1, shfl_xor_h2(a1, o));
        a2 = __hadd2(a2, shfl_xor_h2(a2, o));
        a3 = __hadd2(a3, shfl_xor_h2(a3, o));
    }

    const bool valid = (g == 0) && lactive;
    float2 f0 = __half22float2(a0), f1 = __half22float2(a1);
    float2 f2 = __half22float2(a2), f3 = __half22float2(a3);

    if (!FINAL) {
        if (valid) {
            const float4 b0 = reinterpret_cast<const float4*>(bias)[2 * gl];
            const float4 b1 = reinterpret_cast<const float4*>(bias)[2 * gl + 1];
            float v0 = fmaxf(f0.x + b0.x, 0.f), v1 = fmaxf(f0.y + b0.y, 0.f);
            float v2 = fmaxf(f1.x + b0.z, 0.f), v3 = fmaxf(f1.y + b0.w, 0.f);
            float v4 = fmaxf(f2.x + b1.x, 0.f), v5 = fmaxf(f2.y + b1.y, 0.f);
            float v6 = fmaxf(f3.x + b1.z, 0.f), v7 = fmaxf(f3.y + b1.w, 0.f);
            union { __half2 h2[4]; uint4 u; } pk;
            pk.h2[0] = __floats2half2_rn(v0, v1);
            pk.h2[1] = __floats2half2_rn(v2, v3);
            pk.h2[2] = __floats2half2_rn(v4, v5);
            pk.h2[3] = __floats2half2_rn(v6, v7);
            *reinterpret_cast<uint4*>(reinterpret_cast<__half*>(outp) + (size_t)d * C + 8 * gl) = pk.u;
        }
    } else {
        float v[8];
        float mm = -1e30f;
        if (valid) {
            const float4 b0 = reinterpret_cast<const float4*>(bias)[2 * gl];
            const float4 b1 = reinterpret_cast<const float4*>(bias)[2 * gl + 1];
            v[0] = f0.x + b0.x; v[1] = f0.y + b0.y; v[2] = f1.x + b0.z; v[3] = f1.y + b0.w;
            v[4] = f2.x + b1.x; v[5] = f2.y + b1.y; v[6] = f3.x + b1.z; v[7] = f3.y + b1.w;
#pragma unroll
            for (int j = 0; j < 8; j++) mm = fmaxf(mm, v[j]);
        }
#pragma unroll
        for (int o = 1; o <= 4; o <<= 1) mm = fmaxf(mm, __shfl_xor(mm, o));
        float ex = 0.f;
        if (valid) {
#pragma unroll
            for (int j = 0; j < 8; j++) ex += __expf(v[j] - mm);
        }
#pragma unroll
        for (int o = 1; o <= 4; o <<= 1) ex += __shfl_xor(ex, o);
        if (valid) {
            float lse = mm + logf(ex);
            float4 o0v, o1v;
            o0v.x = v[0] - lse; o0v.y = v[1] - lse; o0v.z = v[2] - lse; o0v.w = v[3] - lse;
            o1v.x = v[4] - lse; o1v.y = v[5] - lse; o1v.z = v[6] - lse; o1v.w = v[7] - lse;
            float* orow = reinterpret_cast<float*>(outp) + (size_t)d * C + 8 * gl;
            *reinterpret_cast<float4*>(orow) = o0v;
            *reinterpret_cast<float4*>(orow + 4) = o1v;
        }
    }
}

extern "C" void kernel_launch(void* const* d_in, const int* in_sizes, int n_in,
                              void* d_out, int out_size, void* d_ws, size_t ws_size,
                              hipStream_t stream) {
    const float* x   = (const float*)d_in[0];
    const int*   ei  = (const int*)d_in[1];
    const float* W1  = (const float*)d_in[2];
    const float* as1 = (const float*)d_in[3];
    const float* ad1 = (const float*)d_in[4];
    const float* b1  = (const float*)d_in[5];
    const float* W2  = (const float*)d_in[6];
    const float* as2 = (const float*)d_in[7];
    const float* ad2 = (const float*)d_in[8];
    const float* b2  = (const float*)d_in[9];
    float* out = (float*)d_out;

    char* p = (char*)d_ws;
    auto alloc = [&](size_t bytes) { void* r = p; p += (bytes + 63) & ~(size_t)63; return r; };

    __half* h16 = (__half*)alloc((size_t)N_NODES * 64 * sizeof(__half));   // 12.8 MB
    int* buck   = (int*)alloc((size_t)NBUCK * BCAP * sizeof(int));         // 8.03 MB
    __half* B16 = (__half*)alloc((size_t)N_NODES * 64 * sizeof(__half));   // 12.8 MB
    float* als  = (float*)alloc((size_t)N_NODES * sizeof(float));
    float* ald  = (float*)alloc((size_t)N_NODES * sizeof(float));
    int* off    = (int*)alloc((size_t)N_NODES * sizeof(int));
    int* deg    = (int*)alloc((size_t)N_NODES * sizeof(int));
    int* bcur   = (int*)alloc((size_t)NBUCK * 16 * sizeof(int));
    int* ssrc   = (int*)alloc((size_t)NBUCK * BCAP * sizeof(int));         // 8.03 MB

    const int* srcA = ei;
    const int* dstA = ei + N_EDGESC;

    hipMemsetAsync(bcur, 0, (size_t)NBUCK * 16 * sizeof(int), stream);
    fused1_kernel<<<NB1 + NG1, 256, 0, stream>>>(srcA, dstA, bcur, buck,
                                                 x, W1, as1, ad1, h16, als, ald);
    bucket2_kernel<<<NBUCK, 512, 0, stream>>>(bcur, buck, ssrc, off, deg);

    // ---- layer 1 aggregation ----
    agg_kernel<HID, false, __half><<<(N_NODES + 3) / 4, 256, 0, stream>>>(
        off, deg, ssrc, als, ald, h16, b1, B16);

    // ---- layer 2 ----
    gemm2_kernel<<<(N_NODES + 127) / 128, 256, 0, stream>>>(B16, W2, as2, ad2, h16, als, ald);
    agg_kernel<OUTC, true, float><<<(N_NODES + 3) / 4, 256, 0, stream>>>(
        off, deg, ssrc, als, ald, h16, b2, out);
}

// Round 19
// 164.135 us; speedup vs baseline: 1.2159x; 1.0081x over previous
//
#include <hip/hip_runtime.h>
#include <hip/hip_fp16.h>

#define N_NODES 100000
#define N_EDGESC 1600000
#define ETOT (N_EDGESC + N_NODES)
#define IN_CH 128
#define HID 64
#define OUTC 40
#define NEG_SLOPE 0.2f
#define BNODES 512                                   // nodes per bucket
#define NBUCK ((N_NODES + BNODES - 1) / BNODES)      // 196
#define BCAP 10240                                   // edge slots per bucket
#define TILE 8192                                    // edges per bucket1 block
#define EPT (TILE / 256)
#define NB1 ((ETOT + TILE - 1) / TILE)               // 208 bucket1 blocks
#define NG1 ((N_NODES + 127) / 128)                  // 782 gemm1 blocks

// ================= fused: bucket1 (sort pass 1) ∥ gemm1 — independent work =========
union FusedSmem {
    struct { int hist[256]; int lofs[256]; int gbase[256]; int cur[256]; int stage[TILE]; } b;
    struct { float Ws[IN_CH * HID]; float as_s[HID]; float ad_s[HID]; } g;
};

__global__ __launch_bounds__(256) void fused1_kernel(
    const int* __restrict__ src, const int* __restrict__ dst,
    int* __restrict__ bcur, int* __restrict__ buck,
    const float* __restrict__ x, const float* __restrict__ W1,
    const float* __restrict__ a_src, const float* __restrict__ a_dst,
    __half* __restrict__ h1, float* __restrict__ als, float* __restrict__ ald) {
    __shared__ FusedSmem sm;
    const int t = threadIdx.x;

    if (blockIdx.x < NB1) {
        // ---------------- bucket1 body ----------------
        const int t0 = blockIdx.x * TILE;
        sm.b.hist[t] = 0;
        __syncthreads();

        int payload[EPT];
        int bkt[EPT];
#pragma unroll
        for (int j = 0; j < EPT; j++) {
            int i = t0 + j * 256 + t;
            if (i < ETOT) {
                int s, d;
                if (i < N_EDGESC) { s = src[i]; d = dst[i]; } else { s = d = i - N_EDGESC; }
                int b = d / BNODES;
                bkt[j] = b;
                payload[j] = ((d & (BNODES - 1)) << 17) | s;
                atomicAdd(&sm.b.hist[b], 1);
            } else {
                bkt[j] = -1;
                payload[j] = 0;
            }
        }
        __syncthreads();

        int hv = sm.b.hist[t];
        sm.b.lofs[t] = hv;
        __syncthreads();
        for (int o = 1; o < 256; o <<= 1) {
            int v = (t >= o) ? sm.b.lofs[t - o] : 0;
            __syncthreads();
            sm.b.lofs[t] += v;
            __syncthreads();
        }
        sm.b.cur[t] = sm.b.lofs[t] - hv;
        if (t < NBUCK && hv > 0) sm.b.gbase[t] = t * BCAP + atomicAdd(&bcur[t * 16], hv);
        __syncthreads();

#pragma unroll
        for (int j = 0; j < EPT; j++) {
            if (bkt[j] >= 0) {
                int p = atomicAdd(&sm.b.cur[bkt[j]], 1);
                sm.b.stage[p] = payload[j];
            }
        }
        __syncthreads();

        const int wv = t >> 6;
        const int lane = t & 63;
        for (int b = wv; b < NBUCK; b += 4) {
            int cntb = sm.b.hist[b];
            if (cntb == 0) continue;
            int lo = sm.b.lofs[b] - cntb;
            int gb = sm.b.gbase[b];
            for (int k = lane; k < cntb; k += 64) buck[gb + k] = sm.b.stage[lo + k];
        }
    } else {
        // ---------------- gemm1 body (quad/2-nodes, 16 interleaved ch) ----------------
        for (int v = t; v < IN_CH * HID; v += 256) sm.g.Ws[v] = W1[v];
        if (t < HID) { sm.g.as_s[t] = a_src[t]; sm.g.ad_s[t] = a_dst[t]; }
        __syncthreads();
        const int n0 = (blockIdx.x - NB1) * 128 + (t >> 2) * 2;
        const int c = t & 3;
        if (n0 >= N_NODES) return;

        float acc0[16], acc1[16];
#pragma unroll
        for (int i = 0; i < 16; i++) { acc0[i] = 0.f; acc1[i] = 0.f; }

        const float4* xr0 = reinterpret_cast<const float4*>(x + (size_t)n0 * IN_CH);
        const float4* xr1 = reinterpret_cast<const float4*>(x + (size_t)(n0 + 1) * IN_CH);
#pragma unroll 2
        for (int kq = 0; kq < IN_CH / 4; kq++) {
            float4 xv0 = xr0[kq];
            float4 xv1 = xr1[kq];
#pragma unroll
            for (int jj = 0; jj < 4; jj++) {
                float xs0 = (jj == 0) ? xv0.x : (jj == 1) ? xv0.y : (jj == 2) ? xv0.z : xv0.w;
                float xs1 = (jj == 0) ? xv1.x : (jj == 1) ? xv1.y : (jj == 2) ? xv1.z : xv1.w;
                const float4* wr = reinterpret_cast<const float4*>(&sm.g.Ws[(kq * 4 + jj) * HID + c * 4]);
#pragma unroll
                for (int j = 0; j < 4; j++) {
                    float4 wv = wr[j * 4];
                    acc0[j * 4 + 0] += xs0 * wv.x; acc1[j * 4 + 0] += xs1 * wv.x;
                    acc0[j * 4 + 1] += xs0 * wv.y; acc1[j * 4 + 1] += xs1 * wv.y;
                    acc0[j * 4 + 2] += xs0 * wv.z; acc1[j * 4 + 2] += xs1 * wv.z;
                    acc0[j * 4 + 3] += xs0 * wv.w; acc1[j * 4 + 3] += xs1 * wv.w;
                }
            }
        }

        float s10 = 0.f, s20 = 0.f, s11 = 0.f, s21 = 0.f;
#pragma unroll
        for (int j = 0; j < 4; j++) {
            int cb = j * 16 + c * 4;
#pragma unroll
            for (int i = 0; i < 4; i++) {
                s10 += acc0[j * 4 + i] * sm.g.as_s[cb + i];
                s20 += acc0[j * 4 + i] * sm.g.ad_s[cb + i];
                s11 += acc1[j * 4 + i] * sm.g.as_s[cb + i];
                s21 += acc1[j * 4 + i] * sm.g.ad_s[cb + i];
            }
            union { __half2 h2[2]; uint2 u; } p0, p1;
            p0.h2[0] = __floats2half2_rn(acc0[j * 4 + 0], acc0[j * 4 + 1]);
            p0.h2[1] = __floats2half2_rn(acc0[j * 4 + 2], acc0[j * 4 + 3]);
            p1.h2[0] = __floats2half2_rn(acc1[j * 4 + 0], acc1[j * 4 + 1]);
            p1.h2[1] = __floats2half2_rn(acc1[j * 4 + 2], acc1[j * 4 + 3]);
            *reinterpret_cast<uint2*>(h1 + (size_t)n0 * HID + cb) = p0.u;
            *reinterpret_cast<uint2*>(h1 + (size_t)(n0 + 1) * HID + cb) = p1.u;
        }
        s10 += __shfl_xor(s10, 1); s10 += __shfl_xor(s10, 2);
        s20 += __shfl_xor(s20, 1); s20 += __shfl_xor(s20, 2);
        s11 += __shfl_xor(s11, 1); s11 += __shfl_xor(s11, 2);
        s21 += __shfl_xor(s21, 1); s21 += __shfl_xor(s21, 2);
        if (c == 0) {
            als[n0] = s10; ald[n0] = s20;
            als[n0 + 1] = s11; ald[n0 + 1] = s21;
        }
    }
}

// ---- pass 2 (1024 threads): one block per bucket; local histogram+scan; LDS-cursor scatter ----
__global__ __launch_bounds__(1024) void bucket2_kernel(const int* __restrict__ bcur,
                                                       const int* __restrict__ buck,
                                                       int* __restrict__ ssrc,
                                                       int* __restrict__ off,
                                                       int* __restrict__ deg) {
    __shared__ int h5[BNODES];
    __shared__ int sdata[256];
    __shared__ int lcur[BNODES];
    const int b = blockIdx.x;
    const int t = threadIdx.x;
    const int base0 = b * BNODES;
    const int bbase = b * BCAP;
    const int cnt_b = bcur[b * 16];           // count (bases were b*BCAP + count)

    if (t < BNODES) h5[t] = 0;
    __syncthreads();
    for (int i = t; i < cnt_b; i += 1024) atomicAdd(&h5[buck[bbase + i] >> 17], 1);
    __syncthreads();

    int c0 = 0, c1 = 0, s = 0;
    if (t < 256) {
        c0 = h5[2 * t]; c1 = h5[2 * t + 1];
        s = c0 + c1;
        sdata[t] = s;
    }
    __syncthreads();
    for (int o = 1; o < 256; o <<= 1) {
        int v = (t < 256 && t >= o) ? sdata[t - o] : 0;
        __syncthreads();
        if (t < 256) sdata[t] += v;
        __syncthreads();
    }
    if (t < 256) {
        int run = sdata[t] - s;
        int e0 = bbase + run, e1 = bbase + run + c0;
        int n0 = base0 + 2 * t, n1 = n0 + 1;
        if (n0 < N_NODES) { off[n0] = e0; deg[n0] = c0; }
        if (n1 < N_NODES) { off[n1] = e1; deg[n1] = c1; }
        lcur[2 * t] = e0; lcur[2 * t + 1] = e1;
    }
    __syncthreads();

    for (int i = t; i < cnt_b; i += 1024) {
        int w = buck[bbase + i];
        int pos = atomicAdd(&lcur[w >> 17], 1);
        ssrc[pos] = w & 0x1FFFF;
    }
}

// ================= GEMM2: quad/2-nodes, 10 interleaved ch, W-read reuse x2 =========
__global__ __launch_bounds__(256) void gemm2_kernel(
    const __half* __restrict__ hin, const float* __restrict__ W2,
    const float* __restrict__ a_src, const float* __restrict__ a_dst,
    __half* __restrict__ h2, float* __restrict__ als, float* __restrict__ ald) {
    __shared__ float Ws[HID * OUTC];
    __shared__ float as_s[OUTC], ad_s[OUTC];
    for (int v = threadIdx.x; v < HID * OUTC; v += 256) Ws[v] = W2[v];
    if (threadIdx.x < OUTC) { as_s[threadIdx.x] = a_src[threadIdx.x]; ad_s[threadIdx.x] = a_dst[threadIdx.x]; }
    __syncthreads();
    const int t = threadIdx.x;
    const int n0 = blockIdx.x * 128 + (t >> 2) * 2;
    const int c = t & 3;
    if (n0 >= N_NODES) return;

    float acc0[10], acc1[10];
#pragma unroll
    for (int i = 0; i < 10; i++) { acc0[i] = 0.f; acc1[i] = 0.f; }

    const uint4* xr0 = reinterpret_cast<const uint4*>(hin + (size_t)n0 * HID);
    const uint4* xr1 = reinterpret_cast<const uint4*>(hin + (size_t)(n0 + 1) * HID);
#pragma unroll
    for (int kq = 0; kq < HID / 8; kq++) {
        union { uint4 u; __half2 h[4]; } u0, u1;
        u0.u = xr0[kq];
        u1.u = xr1[kq];
        float x0[8], x1[8];
#pragma unroll
        for (int j = 0; j < 4; j++) {
            float2 f0 = __half22float2(u0.h[j]);
            float2 f1 = __half22float2(u1.h[j]);
            x0[2 * j] = f0.x; x0[2 * j + 1] = f0.y;
            x1[2 * j] = f1.x; x1[2 * j + 1] = f1.y;
        }
#pragma unroll
        for (int jj = 0; jj < 8; jj++) {
            float xs0 = x0[jj], xs1 = x1[jj];
            const float2* wr = reinterpret_cast<const float2*>(&Ws[(kq * 8 + jj) * OUTC + c * 2]);
#pragma unroll
            for (int j = 0; j < 5; j++) {
                float2 wv = wr[j * 4];
                acc0[j * 2 + 0] += xs0 * wv.x; acc1[j * 2 + 0] += xs1 * wv.x;
                acc0[j * 2 + 1] += xs0 * wv.y; acc1[j * 2 + 1] += xs1 * wv.y;
            }
        }
    }

    float s10 = 0.f, s20 = 0.f, s11 = 0.f, s21 = 0.f;
#pragma unroll
    for (int j = 0; j < 5; j++) {
        int cb = j * 8 + c * 2;
        s10 += acc0[j * 2 + 0] * as_s[cb] + acc0[j * 2 + 1] * as_s[cb + 1];
        s20 += acc0[j * 2 + 0] * ad_s[cb] + acc0[j * 2 + 1] * ad_s[cb + 1];
        s11 += acc1[j * 2 + 0] * as_s[cb] + acc1[j * 2 + 1] * as_s[cb + 1];
        s21 += acc1[j * 2 + 0] * ad_s[cb] + acc1[j * 2 + 1] * ad_s[cb + 1];
        __half2 p0 = __floats2half2_rn(acc0[j * 2 + 0], acc0[j * 2 + 1]);
        __half2 p1 = __floats2half2_rn(acc1[j * 2 + 0], acc1[j * 2 + 1]);
        *reinterpret_cast<unsigned*>(h2 + (size_t)n0 * OUTC + cb) = *reinterpret_cast<unsigned*>(&p0);
        *reinterpret_cast<unsigned*>(h2 + (size_t)(n0 + 1) * OUTC + cb) = *reinterpret_cast<unsigned*>(&p1);
    }
    s10 += __shfl_xor(s10, 1); s10 += __shfl_xor(s10, 2);
    s20 += __shfl_xor(s20, 1); s20 += __shfl_xor(s20, 2);
    s11 += __shfl_xor(s11, 1); s11 += __shfl_xor(s11, 2);
    s21 += __shfl_xor(s21, 1); s21 += __shfl_xor(s21, 2);
    if (c == 0) {
        als[n0] = s10; ald[n0] = s20;
        als[n0 + 1] = s11; ald[n0 + 1] = s21;
    }
}

// ================= agg v6b: prefetched gathers + wave-uniform deg<=16 fast path =====
__device__ __forceinline__ __half2 shfl_xor_h2(__half2 v, int o) {
    int i = *reinterpret_cast<int*>(&v);
    i = __shfl_xor(i, o);
    return *reinterpret_cast<__half2*>(&i);
}

template <int C, bool FINAL, typename OutT>
__global__ __launch_bounds__(256) void agg_kernel(
    const int* __restrict__ off, const int* __restrict__ degs,
    const int* __restrict__ ssrc,
    const float* __restrict__ als, const float* __restrict__ ald,
    const __half* __restrict__ h, const float* __restrict__ bias,
    OutT* __restrict__ outp) {
    const int lane = threadIdx.x & 63;
    const int d = (blockIdx.x * 256 + threadIdx.x) >> 6;
    if (d >= N_NODES) return;
    const int o0 = off[d];
    const int deg = degs[d];
    const float aldd = ald[d];

    int myS = 0;
    float myW = 0.f;
    if (lane < deg) {
        myS = ssrc[o0 + lane];
        float e = als[myS] + aldd;
        e = e > 0.f ? e : NEG_SLOPE * e;
        myW = __expf(e);
    }

    constexpr int GL = (C + 7) / 8;
    const int g = lane >> 3;
    const int gl = lane & 7;
    const bool lactive = (gl < GL);
    const int dmax = min(deg, 64);
    const bool big = (dmax > 16);                     // wave-uniform

    // ---- prefetch first (16 or 32) edges' h rows BEFORE the reduce ----
    int ps0 = __shfl(myS, g);
    int ps1 = __shfl(myS, 8 + g);
    const bool pv0 = lactive && (g < dmax);
    const bool pv1 = lactive && (8 + g < dmax);
    uint4 P0 = {0, 0, 0, 0}, P1 = P0, P2 = P0, P3 = P0;
    bool pv2 = false, pv3 = false;
    if (pv0) P0 = *reinterpret_cast<const uint4*>(h + (size_t)ps0 * C + 8 * gl);
    if (pv1) P1 = *reinterpret_cast<const uint4*>(h + (size_t)ps1 * C + 8 * gl);
    if (big) {
        int ps2 = __shfl(myS, 16 + g);
        int ps3 = __shfl(myS, 24 + g);
        pv2 = lactive && (16 + g < dmax);
        pv3 = lactive && (24 + g < dmax);
        if (pv2) P2 = *reinterpret_cast<const uint4*>(h + (size_t)ps2 * C + 8 * gl);
        if (pv3) P3 = *reinterpret_cast<const uint4*>(h + (size_t)ps3 * C + 8 * gl);
    }

    // ---- softmax denominator (overlaps with the in-flight prefetches) ----
    float sloc = myW;
    for (int t = 64 + lane; t < deg; t += 64) {       // rare tail (deg > 64)
        int s = ssrc[o0 + t];
        float e = als[s] + aldd;
        e = e > 0.f ? e : NEG_SLOPE * e;
        sloc += __expf(e);
    }
#pragma unroll
    for (int o = 32; o; o >>= 1) sloc += __shfl_xor(sloc, o);
    const float inv = 1.0f / (sloc + 1e-16f);
    __half2 mywn2 = __float2half2_rn(myW * inv);
    const int myWbits = *reinterpret_cast<const int*>(&mywn2);

    __half2 a0 = __float2half2_rn(0.f), a1 = a0, a2 = a0, a3 = a0;
    auto fmaP = [&](uint4 u, int wbits) {
        __half2 wn2 = *reinterpret_cast<__half2*>(&wbits);
        union { uint4 u4; __half2 h2[4]; } uu;
        uu.u4 = u;
        a0 = __hfma2(uu.h2[0], wn2, a0);
        a1 = __hfma2(uu.h2[1], wn2, a1);
        a2 = __hfma2(uu.h2[2], wn2, a2);
        a3 = __hfma2(uu.h2[3], wn2, a3);
    };
    auto body = [&](int s, int wbits) {
        uint4 u = *reinterpret_cast<const uint4*>(h + (size_t)s * C + 8 * gl);
        fmaP(u, wbits);
    };

    // prefetched edges
    {
        int w0 = __shfl(myWbits, g);
        int w1 = __shfl(myWbits, 8 + g);
        if (pv0) fmaP(P0, w0);
        if (pv1) fmaP(P1, w1);
        if (big) {
            int w2 = __shfl(myWbits, 16 + g);
            int w3 = __shfl(myWbits, 24 + g);
            if (pv2) fmaP(P2, w2);
            if (pv3) fmaP(P3, w3);
        }
    }
    // rare rounds 32,48
    for (int base = 32; base < dmax; base += 16) {
        int t0 = base + g;
        int t1 = base + 8 + g;
        int s0 = __shfl(myS, t0 & 63), w0 = __shfl(myWbits, t0 & 63);
        int s1 = __shfl(myS, t1 & 63), w1 = __shfl(myWbits, t1 & 63);
        if (lactive && t0 < dmax) body(s0, w0);
        if (lactive && t1 < dmax) body(s1, w1);
    }
    for (int t2 = 64 + g; t2 < deg; t2 += 8) {        // rare tail (deg > 64)
        int s = ssrc[o0 + t2];
        float e = als[s] + aldd;
        e = e > 0.f ? e : NEG_SLOPE * e;
        __half2 wn2 = __float2half2_rn(__expf(e) * inv);
        if (lactive) body(s, *reinterpret_cast<int*>(&wn2));
    }

#pragma unroll
    for (int o = 8; o <= 32; o <<= 1) {
        a0 = __hadd2(a0, shfl_xor_h2(a0, o));
        a1 = __hadd2(a1, shfl_xor_h2(a1, o));
        a2 = __hadd2(a2, shfl_xor_h2(a2, o));
        a3 = __hadd2(a3, shfl_xor_h2(a3, o));
    }

    const bool valid = (g == 0) && lactive;
    float2 f0 = __half22float2(a0), f1 = __half22float2(a1);
    float2 f2 = __half22float2(a2), f3 = __half22float2(a3);

    if (!FINAL) {
        if (valid) {
            const float4 b0 = reinterpret_cast<const float4*>(bias)[2 * gl];
            const float4 b1 = reinterpret_cast<const float4*>(bias)[2 * gl + 1];
            float v0 = fmaxf(f0.x + b0.x, 0.f), v1 = fmaxf(f0.y + b0.y, 0.f);
            float v2 = fmaxf(f1.x + b0.z, 0.f), v3 = fmaxf(f1.y + b0.w, 0.f);
            float v4 = fmaxf(f2.x + b1.x, 0.f), v5 = fmaxf(f2.y + b1.y, 0.f);
            float v6 = fmaxf(f3.x + b1.z, 0.f), v7 = fmaxf(f3.y + b1.w, 0.f);
            union { __half2 h2[4]; uint4 u; } pk;
            pk.h2[0] = __floats2half2_rn(v0, v1);
            pk.h2[1] = __floats2half2_rn(v2, v3);
            pk.h2[2] = __floats2half2_rn(v4, v5);
            pk.h2[3] = __floats2half2_rn(v6, v7);
            *reinterpret_cast<uint4*>(reinterpret_cast<__half*>(outp) + (size_t)d * C + 8 * gl) = pk.u;
        }
    } else {
        float v[8];
        float mm = -1e30f;
        if (valid) {
            const float4 b0 = reinterpret_cast<const float4*>(bias)[2 * gl];
            const float4 b1 = reinterpret_cast<const float4*>(bias)[2 * gl + 1];
            v[0] = f0.x + b0.x; v[1] = f0.y + b0.y; v[2] = f1.x + b0.z; v[3] = f1.y + b0.w;
            v[4] = f2.x + b1.x; v[5] = f2.y + b1.y; v[6] = f3.x + b1.z; v[7] = f3.y + b1.w;
#pragma unroll
            for (int j = 0; j < 8; j++) mm = fmaxf(mm, v[j]);
        }
#pragma unroll
        for (int o = 1; o <= 4; o <<= 1) mm = fmaxf(mm, __shfl_xor(mm, o));
        float ex = 0.f;
        if (valid) {
#pragma unroll
            for (int j = 0; j < 8; j++) ex += __expf(v[j] - mm);
        }
#pragma unroll
        for (int o = 1; o <= 4; o <<= 1) ex += __shfl_xor(ex, o);
        if (valid) {
            float lse = mm + logf(ex);
            float4 o0v, o1v;
            o0v.x = v[0] - lse; o0v.y = v[1] - lse; o0v.z = v[2] - lse; o0v.w = v[3] - lse;
            o1v.x = v[4] - lse; o1v.y = v[5] - lse; o1v.z = v[6] - lse; o1v.w = v[7] - lse;
            float* orow = reinterpret_cast<float*>(outp) + (size_t)d * C + 8 * gl;
            *reinterpret_cast<float4*>(orow) = o0v;
            *reinterpret_cast<float4*>(orow + 4) = o1v;
        }
    }
}

extern "C" void kernel_launch(void* const* d_in, const int* in_sizes, int n_in,
                              void* d_out, int out_size, void* d_ws, size_t ws_size,
                              hipStream_t stream) {
    const float* x   = (const float*)d_in[0];
    const int*   ei  = (const int*)d_in[1];
    const float* W1  = (const float*)d_in[2];
    const float* as1 = (const float*)d_in[3];
    const float* ad1 = (const float*)d_in[4];
    const float* b1  = (const float*)d_in[5];
    const float* W2  = (const float*)d_in[6];
    const float* as2 = (const float*)d_in[7];
    const float* ad2 = (const float*)d_in[8];
    const float* b2  = (const float*)d_in[9];
    float* out = (float*)d_out;

    char* p = (char*)d_ws;
    auto alloc = [&](size_t bytes) { void* r = p; p += (bytes + 63) & ~(size_t)63; return r; };

    __half* h16 = (__half*)alloc((size_t)N_NODES * 64 * sizeof(__half));   // 12.8 MB
    int* buck   = (int*)alloc((size_t)NBUCK * BCAP * sizeof(int));         // 8.03 MB
    __half* B16 = (__half*)alloc((size_t)N_NODES * 64 * sizeof(__half));   // 12.8 MB
    float* als  = (float*)alloc((size_t)N_NODES * sizeof(float));
    float* ald  = (float*)alloc((size_t)N_NODES * sizeof(float));
    int* off    = (int*)alloc((size_t)N_NODES * sizeof(int));
    int* deg    = (int*)alloc((size_t)N_NODES * sizeof(int));
    int* bcur   = (int*)alloc((size_t)NBUCK * 16 * sizeof(int));
    int* ssrc   = (int*)alloc((size_t)NBUCK * BCAP * sizeof(int));         // 8.03 MB

    const int* srcA = ei;
    const int* dstA = ei + N_EDGESC;

    hipMemsetAsync(bcur, 0, (size_t)NBUCK * 16 * sizeof(int), stream);
    fused1_kernel<<<NB1 + NG1, 256, 0, stream>>>(srcA, dstA, bcur, buck,
                                                 x, W1, as1, ad1, h16, als, ald);
    bucket2_kernel<<<NBUCK, 1024, 0, stream>>>(bcur, buck, ssrc, off, deg);

    // ---- layer 1 aggregation ----
    agg_kernel<HID, false, __half><<<(N_NODES + 3) / 4, 256, 0, stream>>>(
        off, deg, ssrc, als, ald, h16, b1, B16);

    // ---- layer 2 ----
    gemm2_kernel<<<(N_NODES + 127) / 128, 256, 0, stream>>>(B16, W2, as2, ad2, h16, als, ald);
    agg_kernel<OUTC, true, float><<<(N_NODES + 3) / 4, 256, 0, stream>>>(
        off, deg, ssrc, als, ald, h16, b2, out);
}